// Round 9
// baseline (297.999 us; speedup 1.0000x reference)
//
#include <hip/hip_runtime.h>
#include <stdint.h>

typedef unsigned short u16;
typedef __bf16 bf16x8 __attribute__((ext_vector_type(8)));
typedef float f32x16 __attribute__((ext_vector_type(16)));
typedef u16 u16x8 __attribute__((ext_vector_type(8)));

__device__ __forceinline__ u16 f2bf(float f) {
  uint32_t u = __float_as_uint(f);
  u += 0x7fffu + ((u >> 16) & 1u);   // round-to-nearest-even
  return (u16)(u >> 16);
}

// ---------------------------------------------------------------------------
// Fragment-order ("swizzled") global layout, shared by cast_x / merge / gemm:
//   X_sw[p][c][lane][j], lane = half*32 + r32, j = 0..7:
//     X_sw(p,c,lane,j) = X[p*32 + r32][c*16 + half*8 + j]
// Element offset of fragment (p,c) = (p*128 + c) * 512   [512 u16/fragment]
// This is exactly the v_mfma_f32_32x32x16_bf16 A/B operand mapping
// (R2-verified): one global_load_dwordx4 per (p,c) = 64 lanes x 16 B
// contiguous = a complete fragment. GEMM then needs NO LDS at all.
// R8 bug: reader used *1024 (byte count) instead of *512 (element count).
// ---------------------------------------------------------------------------

// ---------------------------------------------------------------------------
// build_lr: blocks 0..15 build L4[A_L(128)][B_L(128)][r4(16)] (fp32, 1 MiB),
//           block 16 builds R[A_R(16)][B_R(16)][r4(16)] (fp32, 16 KiB).
// Digit order: A = a0 most significant ... a8 least. Core 7 is bond-swapped.
// ---------------------------------------------------------------------------
__global__ __launch_bounds__(256) void build_lr_kernel(
    const float* __restrict__ p0, const float* __restrict__ p1,
    const float* __restrict__ p2, const float* __restrict__ p3,
    const float* __restrict__ p4, const float* __restrict__ p5,
    const float* __restrict__ p6, const float* __restrict__ p7,
    const float* __restrict__ p8, float* __restrict__ L4, float* __restrict__ R) {
  __shared__ float sA[16384];
  __shared__ float sB[4096];
  const int tid = threadIdx.x;
  if (blockIdx.x < 16) {
    for (int i = tid; i < 1024; i += 256) sA[i] = p0[i];
    __syncthreads();
    // step1: sA[8][8][16] x p1 -> sB[16][16][16]
    for (int i = tid; i < 4096; i += 256) {
      int r = i & 15, t = i >> 4;
      int Bb = t & 15, Aa = t >> 4;
      int a = Aa & 1, A = Aa >> 1, b = Bb & 1, B = Bb >> 1;
      const float* srow = sA + (A * 8 + B) * 16;
      const float* g = p1 + ((a * 2 + b) * 16) * 16 + r;
      float s = 0.f;
#pragma unroll
      for (int l = 0; l < 16; l++) s += srow[l] * g[l * 16];
      sB[i] = s;
    }
    __syncthreads();
    // step2: sB[16][16][16] x p2 -> sA[32][32][16]
    for (int i = tid; i < 16384; i += 256) {
      int r = i & 15, t = i >> 4;
      int Bb = t & 31, Aa = t >> 5;
      int a = Aa & 1, A = Aa >> 1, b = Bb & 1, B = Bb >> 1;
      const float* srow = sB + (A * 16 + B) * 16;
      const float* g = p2 + ((a * 2 + b) * 16) * 16 + r;
      float s = 0.f;
#pragma unroll
      for (int l = 0; l < 16; l++) s += srow[l] * g[l * 16];
      sA[i] = s;
    }
    __syncthreads();
    // fused steps 3+4
    int gi = blockIdx.x * 256 + tid;  // 0..4095
    int b3 = gi & 1, a3 = (gi >> 1) & 1;
    int B2 = (gi >> 2) & 31, A2 = gi >> 7;
    const float* srow = sA + (A2 * 32 + B2) * 16;
    const float* g3 = p3 + ((a3 * 2 + b3) * 16) * 16;
    float tmp[16];
#pragma unroll
    for (int r3 = 0; r3 < 16; r3++) {
      float s = 0.f;
#pragma unroll
      for (int r2 = 0; r2 < 16; r2++) s += srow[r2] * g3[r2 * 16 + r3];
      tmp[r3] = s;
    }
#pragma unroll
    for (int ab = 0; ab < 4; ab++) {
      int a4 = ab >> 1, b4 = ab & 1;
      const float* g4 = p4 + (ab * 16) * 16;
      int AL = A2 * 4 + a3 * 2 + a4;
      int BL = B2 * 4 + b3 * 2 + b4;
      float* drow = L4 + (AL * 128 + BL) * 16;
#pragma unroll
      for (int r4 = 0; r4 < 16; r4++) {
        float s = 0.f;
#pragma unroll
        for (int r3 = 0; r3 < 16; r3++) s += tmp[r3] * g4[r3 * 16 + r4];
        drow[r4] = s;
      }
    }
  } else {
    for (int i = tid; i < 64; i += 256) sA[i] = p8[i];
    __syncthreads();
    // k=7 (bond-swapped)
    for (int i = tid; i < 256; i += 256) {
      int rl = i & 15, t = i >> 4;
      int Bt = t & 3, At = t >> 2;
      int a = At >> 1, Ap = At & 1, b = Bt >> 1, Bp = Bt & 1;
      const float* srow = sA + (Ap * 2 + Bp) * 16;
      const float* g = p7 + ((a * 2 + b) * 16) * 16 + rl;
      float s = 0.f;
#pragma unroll
      for (int rk = 0; rk < 16; rk++) s += srow[rk] * g[rk * 16];
      sB[i] = s;
    }
    __syncthreads();
    // k=6
    for (int i = tid; i < 1024; i += 256) {
      int rl = i & 15, t = i >> 4;
      int Bt = t & 7, At = t >> 3;
      int a = At >> 2, Ap = At & 3, b = Bt >> 2, Bp = Bt & 3;
      const float* srow = sB + (Ap * 4 + Bp) * 16;
      const float* g = p6 + (((a * 2 + b) * 16) + rl) * 16;
      float s = 0.f;
#pragma unroll
      for (int rk = 0; rk < 16; rk++) s += srow[rk] * g[rk];
      sA[i] = s;
    }
    __syncthreads();
    // k=5
    for (int i = tid; i < 4096; i += 256) {
      int rl = i & 15, t = i >> 4;
      int Bt = t & 15, At = t >> 4;
      int a = At >> 3, Ap = At & 7, b = Bt >> 3, Bp = Bt & 7;
      const float* srow = sA + (Ap * 8 + Bp) * 16;
      const float* g = p5 + (((a * 2 + b) * 16) + rl) * 16;
      float s = 0.f;
#pragma unroll
      for (int rk = 0; rk < 16; rk++) s += srow[rk] * g[rk];
      R[i] = s;
    }
  }
}

// ---------------------------------------------------------------------------
// merge: Wsw in FRAGMENT order, thread t = output chunk id (16 B coalesced).
// lane=t&63, c=(t>>6)&127, q=t>>13; n = q*32 + (lane&31);
// k_j = c*16 + (lane>>5)*8 + j.
// W[k][n] = sum_r L4[(k>>4)*128 + (n>>4)][r] * R[(k&15)*16 + (n&15)][r].
// ---------------------------------------------------------------------------
__global__ __launch_bounds__(256) void merge_kernel(const float* __restrict__ L4,
                                                    const float* __restrict__ R,
                                                    u16* __restrict__ Wsw) {
  int t = blockIdx.x * 256 + threadIdx.x;   // 0 .. 524287
  int lane = t & 63;
  int c = (t >> 6) & 127;
  int q = t >> 13;
  int n = q * 32 + (lane & 31);
  int klo = (lane >> 5) * 8;
  const float* lrow = L4 + (c * 128 + (n >> 4)) * 16;
  float lv[16];
#pragma unroll
  for (int r = 0; r < 16; r++) lv[r] = lrow[r];
  const float* rbase = R + (n & 15) * 16;
  u16x8 o;
#pragma unroll
  for (int j = 0; j < 8; j++) {
    const float* rrow = rbase + (klo + j) * 256;
    float s = 0.f;
#pragma unroll
    for (int r = 0; r < 16; r++) s += lv[r] * rrow[r];
    o[j] = f2bf(s);
  }
  *(u16x8*)(Wsw + (size_t)t * 8) = o;
}

// ---------------------------------------------------------------------------
// cast_x: fp32 -> bf16 into FRAGMENT order. Thread t = output chunk id:
// write 16 B at t*8 (perfectly coalesced). Read x[m][k..k+7] (32 B);
// the wave's h=0/h=1 lanes consume complementary 32 B halves of each
// 64 B line, so full lines are used despite the row-gather.
// ---------------------------------------------------------------------------
__global__ __launch_bounds__(256) void cast_x_kernel(const float* __restrict__ x,
                                                     u16* __restrict__ xsw) {
  int t = blockIdx.x * 256 + threadIdx.x;   // 0 .. 2097151
  int lane = t & 63;
  int c = (t >> 6) & 127;
  int p = t >> 13;
  int m = p * 32 + (lane & 31);
  int k = c * 16 + (lane >> 5) * 8;
  const float* src = x + (size_t)m * 2048 + k;
  float4 u = *(const float4*)src;
  float4 v = *(const float4*)(src + 4);
  u16x8 o;
  o[0] = f2bf(u.x); o[1] = f2bf(u.y); o[2] = f2bf(u.z); o[3] = f2bf(u.w);
  o[4] = f2bf(v.x); o[5] = f2bf(v.y); o[6] = f2bf(v.z); o[7] = f2bf(v.w);
  *(u16x8*)(xsw + (size_t)t * 8) = o;
}

// ---------------------------------------------------------------------------
// gemm: C[8192][2048] = A * W, A/B pre-swizzled into fragment order.
// NO LDS, NO barriers: each wave loads fragments straight to VGPRs with
// coalesced 1 KB global_load_dwordx4 per fragment; register triple-buffer
// (prefetch distance 2); compiler inserts fine-grained vmcnt (its strength
// once no barrier forces a drain — m97/m131 lessons).
// Block = 256x256 tile, 4 waves 2x2, wave = 128x128 = 4x4 MFMA.
// bid -> (n=bid&7, m=bid>>3): B-slice (1 MB) L2-resident per XCD;
// A redundancy 8x, B redundancy 32x, both through LLC/L2.
// C/D: col=lane&31, row=(reg&3)+8*(reg>>2)+4*half (m74/m101-verified);
// NT stores keep C (67 MB) out of LLC.
// ---------------------------------------------------------------------------
__global__ __launch_bounds__(256, 1) void gemm_kernel(const u16* __restrict__ A,
                                                      const u16* __restrict__ B,
                                                      float* __restrict__ C) {
  const int tid = threadIdx.x;
  const int lane = tid & 63;
  const int w = tid >> 6;
  const int bid = blockIdx.x;
  const int n_idx = bid & 7;
  const int m_idx = bid >> 3;
  const int M0 = m_idx * 256;
  const int N0 = n_idx * 256;
  const int r32 = lane & 31;
  const int half = lane >> 5;
  const int wm = (w >> 1) * 128;
  const int wn = (w & 1) * 128;
  const int pw0 = (M0 + wm) >> 5;   // first A panel for this wave
  const int qw0 = (N0 + wn) >> 5;   // first B panel for this wave

  // panel stride = 128 frags * 512 elem = 65536; frag(p,c) at (p*128+c)*512
  const u16* a0 = A + (size_t)pw0 * 65536 + lane * 8;
  const u16* b0 = B + (size_t)qw0 * 65536 + lane * 8;

  bf16x8 af[3][4], bv[3][4];
  f32x16 acc[4][4] = {};

#define LOADC(c, s)                                                          \
  do {                                                                       \
    _Pragma("unroll") for (int mt = 0; mt < 4; mt++)                         \
        af[s][mt] = *(const bf16x8*)(a0 + ((size_t)mt * 128 + (c)) * 512);   \
    _Pragma("unroll") for (int nt = 0; nt < 4; nt++)                         \
        bv[s][nt] = *(const bf16x8*)(b0 + ((size_t)nt * 128 + (c)) * 512);   \
  } while (0)

#define CHUNK(s)                                                             \
  do {                                                                       \
    _Pragma("unroll") for (int mt = 0; mt < 4; mt++)                         \
        _Pragma("unroll") for (int nt = 0; nt < 4; nt++)                     \
            acc[mt][nt] = __builtin_amdgcn_mfma_f32_32x32x16_bf16(           \
                af[s][mt], bv[s][nt], acc[mt][nt], 0, 0, 0);                 \
  } while (0)

  LOADC(0, 0);
  LOADC(1, 1);
#pragma unroll 2
  for (int t3 = 0; t3 < 42; t3++) {
    const int c = t3 * 3;
    LOADC(c + 2, 2); CHUNK(0);
    LOADC(c + 3, 0); CHUNK(1);
    LOADC(c + 4, 1); CHUNK(2);
  }
  CHUNK(0);   // c = 126
  CHUNK(1);   // c = 127

#undef LOADC
#undef CHUNK

#pragma unroll
  for (int mt = 0; mt < 4; mt++) {
#pragma unroll
    for (int nt = 0; nt < 4; nt++) {
      size_t cbase = (size_t)(M0 + wm + mt * 32 + 4 * half) * 2048 + (N0 + wn + nt * 32 + r32);
#pragma unroll
      for (int reg = 0; reg < 16; reg++) {
        int row = (reg & 3) + 8 * (reg >> 2);   // + 4*half folded into cbase
        __builtin_nontemporal_store(acc[mt][nt][reg], C + cbase + (size_t)row * 2048);
      }
    }
  }
}

extern "C" void kernel_launch(void* const* d_in, const int* in_sizes, int n_in,
                              void* d_out, int out_size, void* d_ws, size_t ws_size,
                              hipStream_t stream) {
  const float* x = (const float*)d_in[0];
  const float* p0 = (const float*)d_in[1];
  const float* p1 = (const float*)d_in[2];
  const float* p2 = (const float*)d_in[3];
  const float* p3 = (const float*)d_in[4];
  const float* p4 = (const float*)d_in[5];
  const float* p5 = (const float*)d_in[6];
  const float* p6 = (const float*)d_in[7];
  const float* p7 = (const float*)d_in[8];
  const float* p8 = (const float*)d_in[9];
  char* ws = (char*)d_ws;
  // ws layout (bytes): xsw 33554432 | Wsw 8388608 | L4 1048576 | R 16384
  u16* xsw = (u16*)ws;
  u16* Wsw = (u16*)(ws + 33554432);
  float* L4 = (float*)(ws + 41943040);
  float* R = (float*)(ws + 42991616);

  build_lr_kernel<<<17, 256, 0, stream>>>(p0, p1, p2, p3, p4, p5, p6, p7, p8, L4, R);
  merge_kernel<<<2048, 256, 0, stream>>>(L4, R, Wsw);
  cast_x_kernel<<<8192, 256, 0, stream>>>(x, xsw);
  gemm_kernel<<<256, 256, 0, stream>>>(xsw, Wsw, (float*)d_out);
}